// Round 1
// baseline (425.818 us; speedup 1.0000x reference)
//
#include <hip/hip_runtime.h>

#define NV 15000
#define ND 16
#define NR 3
#define NC 32
#define NFDIM 64
#define BB 2

typedef short bf16x8 __attribute__((ext_vector_type(8)));
typedef float f32x4 __attribute__((ext_vector_type(4)));

// ws layout (bytes):
//   y_t  bf16 [NV][16][2][32]          : 30,720,000
//   kb   bf16 [48][4][64][8]           :    196,608
//   pidx int32 [NV*48]                 :  2,880,000
#define YT_BYTES   30720000u
#define KB_OFF     30720000u
#define KB_BYTES   196608u
#define IDX_OFF    30916608u
#define IDX_BYTES  2880000u
#define WS_NEEDED  33796608u

__device__ __forceinline__ unsigned short f2bf(float x) {
  union { float f; unsigned int u; } cv; cv.f = x;
  unsigned int u = cv.u;
  u += 0x7FFF + ((u >> 16) & 1);          // round to nearest even
  return (unsigned short)(u >> 16);
}

// y (B,NV,16,32) fp32 -> y_t (NV,16,B,32) bf16.  One thread per 8 elements.
__global__ void prep_y(const float* __restrict__ y, unsigned short* __restrict__ yt) {
  int tid = blockIdx.x * 256 + threadIdx.x;
  if (tid >= (NV * ND * BB * NC) / 8) return;
  int o   = tid * 8;
  int v   = o >> 10;          // /(16*2*32)
  int rem = o & 1023;
  int d   = rem >> 6;
  int b   = (rem >> 5) & 1;
  int c0  = rem & 31;         // 0,8,16,24
  const float* src = y + (((b * NV + v) * ND + d) * NC + c0);
  unsigned short* dst = yt + o;
#pragma unroll
  for (int i = 0; i < 8; i++) dst[i] = f2bf(src[i]);
}

// kernel (3,16,32,64) fp32 -> kb in MFMA B-fragment layout:
// kb[((chunk*4 + ft)*64 + lane)*8 + j] = kernel[chunk][k=(lane>>4)*8+j][f=ft*16+(lane&15)]
__global__ void prep_kb(const float* __restrict__ kern, unsigned short* __restrict__ kb) {
  int t = blockIdx.x * 256 + threadIdx.x;   // [0, 48*4*64)
  if (t >= 48 * 4 * 64) return;
  int lane  = t & 63;
  int ft    = (t >> 6) & 3;
  int chunk = t >> 8;
  int q = lane >> 4;
  int f = ft * 16 + (lane & 15);
  unsigned short* dst = kb + t * 8;
#pragma unroll
  for (int j = 0; j < 8; j++) {
    int k = q * 8 + j;
    dst[j] = f2bf(kern[(chunk * NC + k) * NFDIM + f]);
  }
}

// pidx[i] = ft_v[i]*1024 + ft_d[i]*64
__global__ void prep_idx(const int* __restrict__ ftv, const int* __restrict__ ftd,
                         int* __restrict__ pidx) {
  int t = blockIdx.x * 256 + threadIdx.x;
  if (t >= NV * 48) return;
  pidx[t] = ftv[t] * 1024 + ftd[t] * 64;
}

// Main: wave = 64 m-rows (m = v*2+b) x 64 f for one l.  48 K-iters of one
// 16x16x32 bf16 MFMA per (m-tile, f-tile).
__global__ __launch_bounds__(256, 4) void sync_conv_main(
    const unsigned short* __restrict__ yt, const unsigned short* __restrict__ kb,
    const int* __restrict__ pidx, const float* __restrict__ bias,
    float* __restrict__ out) {
  int tid  = threadIdx.x;
  int lane = tid & 63;
  int gid  = blockIdx.x * 4 + (tid >> 6);
  int l    = gid & 15;
  int mg   = gid >> 4;                 // [0,469)
  int q    = lane >> 4;
  int n    = lane & 15;                // A-row m / B,D-col n
  int b    = n & 1;
  int voff = n >> 1;
  int vbase = mg * 32;

  int lane_elem = b * 32 + q * 8;      // offset inside y_t[v][d] molecule
  const unsigned short* kb_lane = kb + lane * 8;

  f32x4 acc[4][4];
#pragma unroll
  for (int i = 0; i < 4; i++)
#pragma unroll
    for (int j = 0; j < 4; j++) acc[i][j] = (f32x4){0.f, 0.f, 0.f, 0.f};

  for (int r = 0; r < NR; r++) {
#pragma unroll 4
    for (int d = 0; d < ND; d++) {
      int dp = (d - l) & 15;
      const unsigned short* kbp = kb_lane + (r * 16 + dp) * 2048;
      bf16x8 bfr[4];
#pragma unroll
      for (int ft = 0; ft < 4; ft++)
        bfr[ft] = *reinterpret_cast<const bf16x8*>(kbp + ft * 512);
#pragma unroll
      for (int mt = 0; mt < 4; mt++) {
        int v = vbase + mt * 8 + voff;
        v = v < NV ? v : NV - 1;                 // clamp tail tile
        int p  = pidx[v * 48 + r * 16 + d];      // vv*1024 + ftd*64
        int dd = ((p >> 6) + l) & 15;
        int off = (p & 0xFFFFFC00) + (dd << 6) + lane_elem;
        bf16x8 afr = *reinterpret_cast<const bf16x8*>(yt + off);
#pragma unroll
        for (int ft = 0; ft < 4; ft++)
          acc[mt][ft] = __builtin_amdgcn_mfma_f32_16x16x32_bf16(
              afr, bfr[ft], acc[mt][ft], 0, 0, 0);
      }
    }
  }

  float bv[4];
#pragma unroll
  for (int ft = 0; ft < 4; ft++) bv[ft] = bias[ft * 16 + n];

#pragma unroll
  for (int mt = 0; mt < 4; mt++) {
#pragma unroll
    for (int reg = 0; reg < 4; reg++) {
      int m  = q * 4 + reg;                      // D row
      int v  = vbase + mt * 8 + (m >> 1);
      int bb = m & 1;
      if (v < NV) {
        float* dst = out + (((bb * NV + v) * ND + l) * NFDIM) + n;
#pragma unroll
        for (int ft = 0; ft < 4; ft++) {
          float x = acc[mt][ft][reg] + bv[ft];
          dst[ft * 16] = x > 0.f ? x : 0.f;
        }
      }
    }
  }
}

// Slow fp32 fallback (only if ws too small): block=(b,v,l), thread=f.
__global__ void fallback_kernel(const float* __restrict__ y, const int* __restrict__ ftv,
                                const int* __restrict__ ftd, const float* __restrict__ kern,
                                const float* __restrict__ bias, float* __restrict__ out) {
  int idx = blockIdx.x;               // b*NV*16 + v*16 + l
  int l = idx & 15;
  int v = (idx >> 4) % NV;
  int b = idx / (NV * ND);
  int f = threadIdx.x;
  float acc = 0.f;
  for (int r = 0; r < NR; r++)
    for (int d = 0; d < ND; d++) {
      int ii = (v * NR + r) * ND + d;
      int vv = ftv[ii];
      int dd = (ftd[ii] + l) & 15;
      int dp = (d - l) & 15;
      const float* yp = y + ((b * NV + vv) * ND + dd) * NC;
      const float* kp = kern + ((r * 16 + dp) * NC) * NFDIM + f;
#pragma unroll 8
      for (int c = 0; c < NC; c++) acc += yp[c] * kp[c * NFDIM];
    }
  float x = acc + bias[f];
  out[idx * NFDIM + f] = x > 0.f ? x : 0.f;
}

extern "C" void kernel_launch(void* const* d_in, const int* in_sizes, int n_in,
                              void* d_out, int out_size, void* d_ws, size_t ws_size,
                              hipStream_t stream) {
  const float* y    = (const float*)d_in[0];
  const int*   ftv  = (const int*)d_in[1];
  const int*   ftd  = (const int*)d_in[2];
  const float* kern = (const float*)d_in[3];
  const float* bias = (const float*)d_in[4];
  float* out = (float*)d_out;

  if (ws_size >= (size_t)WS_NEEDED) {
    char* ws = (char*)d_ws;
    unsigned short* yt = (unsigned short*)ws;
    unsigned short* kb = (unsigned short*)(ws + KB_OFF);
    int* pidx          = (int*)(ws + IDX_OFF);

    prep_y<<<(NV * ND * BB * NC / 8 + 255) / 256, 256, 0, stream>>>(y, yt);
    prep_kb<<<(48 * 4 * 64 + 255) / 256, 256, 0, stream>>>(kern, kb);
    prep_idx<<<(NV * 48 + 255) / 256, 256, 0, stream>>>(ftv, ftd, pidx);
    // 469 m-groups (64 rows each) x 16 l = 7504 waves = 1876 blocks
    sync_conv_main<<<1876, 256, 0, stream>>>(yt, kb, pidx, bias, out);
  } else {
    fallback_kernel<<<BB * NV * ND, NFDIM, 0, stream>>>(y, ftv, ftd, kern, bias, out);
  }
}

// Round 2
// 376.503 us; speedup vs baseline: 1.1310x; 1.1310x over previous
//
#include <hip/hip_runtime.h>

#define NV 15000
#define ND 16
#define NR 3
#define NC 32
#define NFDIM 64
#define BB 2

typedef short bf16x8 __attribute__((ext_vector_type(8)));
typedef float f32x4 __attribute__((ext_vector_type(4)));
typedef unsigned short u16x8 __attribute__((ext_vector_type(8)));

// ws layout (bytes):
//   y_t  bf16 [NV][16][2][32]          : 30,720,000
//   kb   bf16 [48][4][64][8]           :    196,608
#define KB_OFF     30720000u
#define WS_NEEDED  30916608u

__device__ __forceinline__ unsigned short f2bf(float x) {
  union { float f; unsigned int u; } cv; cv.f = x;
  unsigned int u = cv.u;
  u += 0x7FFF + ((u >> 16) & 1);          // round to nearest even
  return (unsigned short)(u >> 16);
}

// y (B,NV,16,32) fp32 -> y_t (NV,16,B,32) bf16. One thread per 8 elems,
// vectorized: 2x float4 load, 1x 16B store.
__global__ void prep_y(const float* __restrict__ y, u16x8* __restrict__ yt) {
  int tid = blockIdx.x * 256 + threadIdx.x;
  if (tid >= (NV * ND * BB * NC) / 8) return;
  int o   = tid * 8;
  int v   = o >> 10;
  int rem = o & 1023;
  int d   = rem >> 6;
  int b   = (rem >> 5) & 1;
  int c0  = rem & 31;
  const f32x4* src = (const f32x4*)(y + (((b * NV + v) * ND + d) * NC + c0));
  f32x4 lo = src[0], hi = src[1];
  u16x8 r;
#pragma unroll
  for (int i = 0; i < 4; i++) { r[i] = f2bf(lo[i]); r[4 + i] = f2bf(hi[i]); }
  yt[tid] = r;
}

// kernel (3,16,32,64) fp32 -> kb in MFMA B-fragment layout with f = 4*col+ft:
// kb[((chunk*4 + ft)*64 + lane)*8 + j] = kernel[chunk][k=(lane>>4)*8+j][f=(lane&15)*4+ft]
__global__ void prep_kb(const float* __restrict__ kern, unsigned short* __restrict__ kb) {
  int t = blockIdx.x * 256 + threadIdx.x;   // [0, 48*4*64)
  if (t >= 48 * 4 * 64) return;
  int lane  = t & 63;
  int ft    = (t >> 6) & 3;
  int chunk = t >> 8;
  int q = lane >> 4;
  int f = (lane & 15) * 4 + ft;
  unsigned short* dst = kb + t * 8;
#pragma unroll
  for (int j = 0; j < 8; j++) {
    int k = q * 8 + j;
    dst[j] = f2bf(kern[(chunk * NC + k) * NFDIM + f]);
  }
}

// Main: block = 4 waves, one m-group of 16 v (32 rows m=v*2+b), waves handle
// l = lg*4 + w. Per wave: 2 m-tiles x 4 f-tiles, 48 K-steps of 16x16x32 MFMA.
// Packed indices staged in LDS; A-fragments prefetched 8-wide per 4-step group.
__global__ __launch_bounds__(256, 4) void sync_conv_main(
    const unsigned short* __restrict__ yt, const unsigned short* __restrict__ kb,
    const int* __restrict__ ftv, const int* __restrict__ ftd,
    const float* __restrict__ bias, float* __restrict__ out) {
  __shared__ int pidx_lds[16][49];   // packed ftv*16+ftd, padded stride

  int tid  = threadIdx.x;
  int lane = tid & 63;
  int mg   = blockIdx.x >> 2;
  int lg   = blockIdx.x & 3;
  int l    = lg * 4 + (tid >> 6);
  int vbase = mg * 16;

  // Stage packed indices: 16 v x 48 (r,d) ints, coalesced.
  for (int t = tid; t < 16 * 48; t += 256) {
    int i = t / 48, j = t - i * 48;
    int v = vbase + i; v = v < NV ? v : NV - 1;
    pidx_lds[i][j] = ftv[v * 48 + j] * 16 + (ftd[v * 48 + j] & 15);
  }
  __syncthreads();

  int q    = lane >> 4;
  int n    = lane & 15;                // A-row group / D col
  int b    = n & 1;
  int voff = n >> 1;
  int lane_elem = b * 32 + q * 8;
  const unsigned short* kb_lane = kb + lane * 8;

  f32x4 acc[2][4];
#pragma unroll
  for (int i = 0; i < 2; i++)
#pragma unroll
    for (int j = 0; j < 4; j++) acc[i][j] = (f32x4){0.f, 0.f, 0.f, 0.f};

  for (int r = 0; r < NR; r++) {
#pragma unroll
    for (int dg = 0; dg < 4; dg++) {
      // prefetch 8 A-fragments (2 mt x 4 d-steps)
      bf16x8 afr[2][4];
#pragma unroll
      for (int mt = 0; mt < 2; mt++)
#pragma unroll
        for (int ds = 0; ds < 4; ds++) {
          int p  = pidx_lds[mt * 8 + voff][r * 16 + dg * 4 + ds];
          int dd = ((p & 15) + l) & 15;
          int off = (p >> 4) * 1024 + (dd << 6) + lane_elem;
          afr[mt][ds] = *reinterpret_cast<const bf16x8*>(yt + off);
        }
#pragma unroll
      for (int ds = 0; ds < 4; ds++) {
        int d  = dg * 4 + ds;
        int dp = (d - l) & 15;
        const unsigned short* kbp = kb_lane + (r * 16 + dp) * 2048;
        bf16x8 bfr[4];
#pragma unroll
        for (int ft = 0; ft < 4; ft++)
          bfr[ft] = *reinterpret_cast<const bf16x8*>(kbp + ft * 512);
#pragma unroll
        for (int mt = 0; mt < 2; mt++)
#pragma unroll
          for (int ft = 0; ft < 4; ft++)
            acc[mt][ft] = __builtin_amdgcn_mfma_f32_16x16x32_bf16(
                afr[mt][ds], bfr[ft], acc[mt][ft], 0, 0, 0);
      }
    }
  }

  f32x4 bv = *reinterpret_cast<const f32x4*>(bias + 4 * n);

#pragma unroll
  for (int mt = 0; mt < 2; mt++) {
#pragma unroll
    for (int reg = 0; reg < 4; reg++) {
      int m  = q * 4 + reg;                      // D row
      int v  = vbase + mt * 8 + (m >> 1);
      int bb = m & 1;
      if (v < NV) {
        f32x4 x;
#pragma unroll
        for (int ft = 0; ft < 4; ft++) {
          float t = acc[mt][ft][reg] + bv[ft];   // f = 4n+ft
          x[ft] = t > 0.f ? t : 0.f;
        }
        float* dst = out + (((bb * NV + v) * ND + l) * NFDIM) + 4 * n;
        __builtin_nontemporal_store(x, (f32x4*)dst);
      }
    }
  }
}

// Slow fp32 fallback (only if ws too small).
__global__ void fallback_kernel(const float* __restrict__ y, const int* __restrict__ ftv,
                                const int* __restrict__ ftd, const float* __restrict__ kern,
                                const float* __restrict__ bias, float* __restrict__ out) {
  int idx = blockIdx.x;               // b*NV*16 + v*16 + l
  int l = idx & 15;
  int v = (idx >> 4) % NV;
  int b = idx / (NV * ND);
  int f = threadIdx.x;
  float acc = 0.f;
  for (int r = 0; r < NR; r++)
    for (int d = 0; d < ND; d++) {
      int ii = (v * NR + r) * ND + d;
      int vv = ftv[ii];
      int dd = (ftd[ii] + l) & 15;
      int dp = (d - l) & 15;
      const float* yp = y + ((b * NV + vv) * ND + dd) * NC;
      const float* kp = kern + ((r * 16 + dp) * NC) * NFDIM + f;
#pragma unroll 8
      for (int c = 0; c < NC; c++) acc += yp[c] * kp[c * NFDIM];
    }
  float x = acc + bias[f];
  out[idx * NFDIM + f] = x > 0.f ? x : 0.f;
}

extern "C" void kernel_launch(void* const* d_in, const int* in_sizes, int n_in,
                              void* d_out, int out_size, void* d_ws, size_t ws_size,
                              hipStream_t stream) {
  const float* y    = (const float*)d_in[0];
  const int*   ftv  = (const int*)d_in[1];
  const int*   ftd  = (const int*)d_in[2];
  const float* kern = (const float*)d_in[3];
  const float* bias = (const float*)d_in[4];
  float* out = (float*)d_out;

  if (ws_size >= (size_t)WS_NEEDED) {
    char* ws = (char*)d_ws;
    unsigned short* yt = (unsigned short*)ws;
    unsigned short* kb = (unsigned short*)(ws + KB_OFF);

    prep_y<<<(NV * ND * BB * NC / 8 + 255) / 256, 256, 0, stream>>>(y, (u16x8*)yt);
    prep_kb<<<(48 * 4 * 64 + 255) / 256, 256, 0, stream>>>(kern, kb);
    // 938 m-groups (16 v each) x 4 l-groups = 3752 blocks x 4 waves
    sync_conv_main<<<3752, 256, 0, stream>>>(yt, kb, ftv, ftd, bias, out);
  } else {
    fallback_kernel<<<BB * NV * ND, NFDIM, 0, stream>>>(y, ftv, ftd, kern, bias, out);
  }
}